// Round 2
// baseline (659.907 us; speedup 1.0000x reference)
//
#include <hip/hip_runtime.h>
#include <math.h>

#define BB 128
#define TT 160
#define CC 6000
#define UU 32
#define SS 65           // 2*U + 1
#define BLANK (CC - 1)
#define NEGV (-1e30f)
#define EPSV (1e-7f)
#define NTHR 1024       // 16 waves for the gather phase

__device__ __forceinline__ float laddexp(float a, float b) {
    // exact mirror of jnp.logaddexp: max + log1p(exp(-|a-b|))
    float m = fmaxf(a, b);
    float d = fabsf(a - b);
    return m + log1pf(expf(-d));
}

__global__ __launch_bounds__(NTHR) void ctc_loss_kernel(
    const int*   __restrict__ y_true,        // [B,U]
    const float* __restrict__ y_pred,        // [B,T,C] probabilities
    const int*   __restrict__ input_length,  // [B,1]
    const int*   __restrict__ label_length,  // [B,1]
    float*       __restrict__ out)           // [B,1] loss
{
    __shared__ float lpb[TT];        // log p(blank) per frame
    __shared__ float lpl[TT * UU];   // log p(label u) per frame
    __shared__ int   yt[UU];

    const int b   = blockIdx.x;
    const int tid = threadIdx.x;

    if (tid < UU) yt[tid] = y_true[b * UU + tid];
    __syncthreads();

    const int len = input_length[b];   // 120..160, frames actually used
    const int L   = label_length[b];   // 8..32

    // ---- stage gathered log-probs into LDS (only rows t < len) ----
    const float* yp = y_pred + (size_t)b * TT * CC;
    // blanks: one load per frame
    for (int t = tid; t < len; t += NTHR)
        lpb[t] = logf(yp[t * CC + BLANK] + EPSV);
    // labels: 32 loads per frame
    const int nl = len * UU;
    for (int idx = tid; idx < nl; idx += NTHR) {
        int t = idx >> 5;
        int u = idx & 31;
        lpl[idx] = logf(yp[t * CC + yt[u]] + EPSV);
    }
    __syncthreads();

    // ---- serial DP on wave 0 only, shuffle-based, no barriers ----
    if (tid >= 64) return;
    const int  lane = tid;
    const bool odd  = lane & 1;
    const int  u    = lane >> 1;

    // skip transition s-2 -> s: s odd, s>=3, label[u] != label[u-1]
    const bool skip = odd && (lane >= 3) && (yt[u] != yt[u - 1]);

    // alpha at t=0: only s=0 (blank) and s=1 (first label) live
    {
        float v0 = odd ? lpl[0] : lpb[0];
        // lane0: even -> lpb[0]; lane1: odd,u=0 -> lpl[0]
        float a = (lane <= 1) ? v0 : NEGV;
        float a64 = NEGV;

        // prefetched row t=1 (len >= 120 guarantees it exists)
        float lpB_cur = lpb[1];
        float lp_cur  = odd ? lpl[UU + u] : lpB_cur;

        for (int t = 1; t < len; ++t) {
            // issue next-row LDS reads early; they hide under the laddexp chain
            int tn = (t + 1 < len) ? t + 1 : t;
            float lpB_nxt = lpb[tn];
            float lp_nxt  = odd ? lpl[tn * UU + u] : lpB_nxt;

            float a63 = __shfl(a, 63);
            float p1  = __shfl_up(a, 1);
            float p2  = __shfl_up(a, 2);
            if (lane < 1) p1 = NEGV;
            if (lane < 2) p2 = NEGV;

            float nv  = laddexp(laddexp(a, p1), skip ? p2 : NEGV) + lp_cur;
            float n64 = laddexp(a64, a63) + lpB_cur;   // s=64: final blank, no skip

            a   = nv;
            a64 = n64;
            lp_cur  = lp_nxt;
            lpB_cur = lpB_nxt;
        }

        // loss = -logaddexp(alpha[2L], alpha[2L-1]),  2L in [16,64]
        const int e = 2 * L;
        float ae  = (e == 64) ? a64 : __shfl(a, e);
        float ae1 = __shfl(a, e - 1);              // e-1 <= 63 always

        if (lane == 0) out[b] = -laddexp(ae, ae1);
    }
}

extern "C" void kernel_launch(void* const* d_in, const int* in_sizes, int n_in,
                              void* d_out, int out_size, void* d_ws, size_t ws_size,
                              hipStream_t stream) {
    const int*   y_true       = (const int*)  d_in[0];
    const float* y_pred       = (const float*)d_in[1];
    const int*   input_length = (const int*)  d_in[2];
    const int*   label_length = (const int*)  d_in[3];
    float*       out          = (float*)      d_out;

    ctc_loss_kernel<<<BB, NTHR, 0, stream>>>(y_true, y_pred, input_length, label_length, out);
}

// Round 4
// 657.531 us; speedup vs baseline: 1.0036x; 1.0036x over previous
//
#include <hip/hip_runtime.h>
#include <math.h>

#define BB 128
#define TT 160
#define CC 6000
#define UU 32
#define S33 33          // 32 labels + blank column
#define BLANK (CC - 1)
#define NEGV (-1e30f)
#define EPSV (1e-7f)

// ws layout: float lp[B][T][33]  (2,703,360 bytes)

__device__ __forceinline__ float laddexp(float a, float b) {
    // exact mirror of jnp.logaddexp: max + log1p(exp(-|a-b|))
    float m = fmaxf(a, b);
    float d = fabsf(a - b);
    return m + log1pf(expf(-d));
}

// ---------- kernel A: full-GPU random gather + log into ws ----------
__global__ __launch_bounds__(256) void ctc_gather_kernel(
    const int*   __restrict__ y_true,        // [B,U]
    const float* __restrict__ y_pred,        // [B,T,C]
    const int*   __restrict__ input_length,  // [B,1]
    float*       __restrict__ lp)            // [B,T,33]
{
    const int id = blockIdx.x * 256 + threadIdx.x;   // 0 .. B*T*33-1
    const int s  = id % S33;
    const int bt = id / S33;
    const int t  = bt % TT;
    const int b  = bt / TT;

    if (t >= input_length[b]) return;        // frozen frames never read

    const int cls = (s == 32) ? BLANK : y_true[b * UU + s];
    const float v = y_pred[((size_t)b * TT + t) * CC + cls];
    lp[id] = logf(v + EPSV);
}

// ---------- kernel B: per-batch serial DP ----------
__global__ __launch_bounds__(256) void ctc_dp_kernel(
    const int*   __restrict__ y_true,        // [B,U]
    const int*   __restrict__ input_length,  // [B,1]
    const int*   __restrict__ label_length,  // [B,1]
    const float* __restrict__ lp,            // [B,T,33]
    float*       __restrict__ out)           // [B,1]
{
    __shared__ float sl[TT * S33];           // 21,120 B

    const int b   = blockIdx.x;
    const int tid = threadIdx.x;
    const int len = input_length[b];         // 120..160
    const int L   = label_length[b];         // 8..32

    // stage lp[b][0..len-1][*] into LDS, coalesced
    const float* src = lp + (size_t)b * TT * S33;
    const int n = len * S33;
    for (int i = tid; i < n; i += 256) sl[i] = src[i];
    __syncthreads();

    if (tid >= 64) return;
    const int  lane = tid;
    const bool odd  = lane & 1;
    const int  u    = lane >> 1;
    const int  col  = odd ? u : 32;          // this lane's class column

    bool skip = false;
    if (odd && lane >= 3)
        skip = y_true[b * UU + u] != y_true[b * UU + u - 1];

    // alpha(t=0): s=0 -> blank, s=1 -> first label
    float a   = (lane == 0) ? sl[32] : (lane == 1) ? sl[0] : NEGV;
    float a64 = NEGV;

    // distance-2 register prefetch (len >= 120 guarantees rows 1,2 exist)
    float c0 = sl[1 * S33 + col], c0B = sl[1 * S33 + 32];   // row t=1
    float c1 = sl[2 * S33 + col], c1B = sl[2 * S33 + 32];   // row t=2

    for (int t = 1; t < len; ++t) {
        int tp = t + 2; if (tp >= len) tp = len - 1;
        float nl = sl[tp * S33 + col];
        float nB = sl[tp * S33 + 32];

        float a63 = __shfl(a, 63);
        float p1  = __shfl_up(a, 1);
        float p2  = __shfl_up(a, 2);
        if (lane < 1) p1 = NEGV;
        if (lane < 2) p2 = NEGV;

        float nv  = laddexp(laddexp(a, p1), skip ? p2 : NEGV) + c0;
        float n64 = laddexp(a64, a63) + c0B;      // s=64: final blank, no skip

        a   = nv;
        a64 = n64;
        c0 = c1; c0B = c1B;
        c1 = nl; c1B = nB;
    }

    // loss = -logaddexp(alpha[2L], alpha[2L-1]),  2L in [16,64]
    const int e = 2 * L;
    float ae  = (e == 64) ? a64 : __shfl(a, e);
    float ae1 = __shfl(a, e - 1);                 // e-1 <= 63 always

    if (lane == 0) out[b] = -laddexp(ae, ae1);
}

extern "C" void kernel_launch(void* const* d_in, const int* in_sizes, int n_in,
                              void* d_out, int out_size, void* d_ws, size_t ws_size,
                              hipStream_t stream) {
    const int*   y_true       = (const int*)  d_in[0];
    const float* y_pred       = (const float*)d_in[1];
    const int*   input_length = (const int*)  d_in[2];
    const int*   label_length = (const int*)  d_in[3];
    float*       out          = (float*)      d_out;
    float*       lp           = (float*)      d_ws;   // 2.7 MB used

    const int total = BB * TT * S33;                  // 675,840
    ctc_gather_kernel<<<total / 256, 256, 0, stream>>>(y_true, y_pred, input_length, lp);
    ctc_dp_kernel<<<BB, 256, 0, stream>>>(y_true, input_length, label_length, lp, out);
}

// Round 5
// 573.008 us; speedup vs baseline: 1.1517x; 1.1475x over previous
//
#include <hip/hip_runtime.h>
#include <math.h>

#define BB 128
#define TT 160
#define CC 6000
#define UU 32
#define S33 33          // 32 labels + blank column
#define BLANK (CC - 1)
#define NEGV (-1e30f)
#define EPSV (1e-7f)

// ws layout: float lp[B][T][33]  (2,703,360 bytes)

// fast 3-way logsumexp: max3 -> one exp/log round-trip.
// Max term contributes exp(0)=1 exactly, so s>=1 and __logf's absolute
// error is ~1e-7 — negligible vs loss magnitudes O(100..1000).
__device__ __forceinline__ float lse3(float a, float b, float c) {
    float m = fmaxf(fmaxf(a, b), c);          // -> v_max3_f32
    float s = __expf(a - m) + __expf(b - m) + __expf(c - m);
    return m + __logf(s);
}
__device__ __forceinline__ float lse2(float a, float b) {
    float m = fmaxf(a, b);
    float s = __expf(a - m) + __expf(b - m);
    return m + __logf(s);
}

// ---------- kernel A: full-GPU random gather + log into ws ----------
__global__ __launch_bounds__(256) void ctc_gather_kernel(
    const int*   __restrict__ y_true,        // [B,U]
    const float* __restrict__ y_pred,        // [B,T,C]
    const int*   __restrict__ input_length,  // [B,1]
    float*       __restrict__ lp)            // [B,T,33]
{
    const int id = blockIdx.x * 256 + threadIdx.x;   // 0 .. B*T*33-1
    const int s  = id % S33;
    const int bt = id / S33;
    const int t  = bt % TT;
    const int b  = bt / TT;

    if (t >= input_length[b]) return;        // frozen frames never read

    const int cls = (s == 32) ? BLANK : y_true[b * UU + s];
    const float v = y_pred[((size_t)b * TT + t) * CC + cls];
    lp[id] = logf(v + EPSV);                 // precise log here (matches ref closely)
}

// ---------- kernel B: per-batch serial DP ----------
__global__ __launch_bounds__(256) void ctc_dp_kernel(
    const int*   __restrict__ y_true,        // [B,U]
    const int*   __restrict__ input_length,  // [B,1]
    const int*   __restrict__ label_length,  // [B,1]
    const float* __restrict__ lp,            // [B,T,33]
    float*       __restrict__ out)           // [B,1]
{
    __shared__ float sl[TT * S33];           // 21,120 B

    const int b   = blockIdx.x;
    const int tid = threadIdx.x;
    const int len = input_length[b];         // 120..160
    const int L   = label_length[b];         // 8..32

    // stage lp[b][0..len-1][*] into LDS, coalesced (L2/L3-hot)
    const float* src = lp + (size_t)b * TT * S33;
    const int n = len * S33;
    for (int i = tid; i < n; i += 256) sl[i] = src[i];
    __syncthreads();

    if (tid >= 64) return;
    const int  lane = tid;
    const bool odd  = lane & 1;
    const int  u    = lane >> 1;
    const int  col  = odd ? u : 32;          // this lane's class column

    bool skip = false;
    if (odd && lane >= 3)
        skip = y_true[b * UU + u] != y_true[b * UU + u - 1];

    // alpha(t=0): s=0 -> blank, s=1 -> first label
    float a   = (lane == 0) ? sl[32] : (lane == 1) ? sl[0] : NEGV;
    float a64 = NEGV;

    // distance-2 register prefetch (len >= 120 guarantees rows 1,2 exist)
    float c0 = sl[1 * S33 + col], c0B = sl[1 * S33 + 32];   // row t=1
    float c1 = sl[2 * S33 + col], c1B = sl[2 * S33 + 32];   // row t=2

    for (int t = 1; t < len; ++t) {
        int tp = t + 2; if (tp >= len) tp = len - 1;
        float nl = sl[tp * S33 + col];
        float nB = sl[tp * S33 + 32];

        float a63 = __shfl(a, 63);
        float p1  = __shfl_up(a, 1);
        float p2  = __shfl_up(a, 2);
        if (lane < 1) p1 = NEGV;
        if (lane < 2) p2 = NEGV;

        float nv  = lse3(a, p1, skip ? p2 : NEGV) + c0;
        float n64 = lse2(a64, a63) + c0B;         // s=64: final blank, no skip

        a   = nv;
        a64 = n64;
        c0 = c1; c0B = c1B;
        c1 = nl; c1B = nB;
    }

    // loss = -logaddexp(alpha[2L], alpha[2L-1]),  2L in [16,64]
    const int e = 2 * L;
    float ae  = (e == 64) ? a64 : __shfl(a, e);
    float ae1 = __shfl(a, e - 1);                 // e-1 <= 63 always

    if (lane == 0) out[b] = -lse2(ae, ae1);
}

extern "C" void kernel_launch(void* const* d_in, const int* in_sizes, int n_in,
                              void* d_out, int out_size, void* d_ws, size_t ws_size,
                              hipStream_t stream) {
    const int*   y_true       = (const int*)  d_in[0];
    const float* y_pred       = (const float*)d_in[1];
    const int*   input_length = (const int*)  d_in[2];
    const int*   label_length = (const int*)  d_in[3];
    float*       out          = (float*)      d_out;
    float*       lp           = (float*)      d_ws;   // 2.7 MB used

    const int total = BB * TT * S33;                  // 675,840
    ctc_gather_kernel<<<total / 256, 256, 0, stream>>>(y_true, y_pred, input_length, lp);
    ctc_dp_kernel<<<BB, 256, 0, stream>>>(y_true, input_length, label_length, lp, out);
}